// Round 1
// baseline (272.916 us; speedup 1.0000x reference)
//
#include <hip/hip_runtime.h>
#include <hip/hip_fp16.h>

// FrameConsistencyLoss: mean over (N,64) of (proj_a - proj_b)^2,
// proj_x[i] = x[i] @ W[ids_x[i]] + b[ids_x[i]]; N=2e6, REL_DIM=14, CAN_DIM=64, 4 experts.
//
// R5: single-buffered LDS (DS ops from one wave are executed in order by the
// LDS FIFO, so with 1-wave blocks the next chunk's scatter-writes can never
// bypass the current chunk's fragment-reads -> no hazard, no barriers).
// Halving LDS (18432 -> 9216 B/block) lifts the LDS occupancy cap from
// 8 to 16 blocks/CU; persistent grid 2048 -> 4096 (__launch_bounds__(64,4)).
// Previous dispatch was latency-bound: MfmaUtil 5.7%, VALUBusy 7%, HBM 14%,
// occupancy 19% -- doubling resident waves/SIMD (2->4) attacks that directly.
//
//   Row r: diff_emb[k]: window 14*ea..+13 gets +a (f16), window 14*eb..+13 gets -b,
//   one-hot +1 at k=56+ea, -1 at k=56+eb (bias rows of W~); if ea==eb the windows
//   merge to (a-b) and the one-hots cancel. D = diff_emb @ W~ via 2 chained
//   mfma_f32_16x16x32_f16 per (row-tile, col-tile); loss += sum(D^2) --
//   invariant to fragment layout permutations (A/B k-mappings are symmetric).

#define N_ROWS   2000000
#define N_CHUNKS (N_ROWS / 64)   // 31250 chunks of 64 rows
#define NBLK     4096            // 16 blocks/CU x 256 CUs, persistent
#define LDSW     36              // dwords per LDS row (64 ushorts data + 8 pad)

typedef _Float16     h8 __attribute__((ext_vector_type(8)));
typedef float        f4 __attribute__((ext_vector_type(4)));
typedef unsigned int u4 __attribute__((ext_vector_type(4)));

__device__ __forceinline__ unsigned int pkrtz(float a, float b) {
    return __builtin_bit_cast(unsigned int, __builtin_amdgcn_cvt_pkrtz(a, b));
}

struct RowRegs {
    float a[14], b[14];
    int ea, eb;
};

__device__ __forceinline__ RowRegs load_chunk(int c, int lane,
        const float* __restrict__ A, const float* __restrict__ B,
        const int* __restrict__ IDA, const int* __restrict__ IDB) {
    RowRegs r;
    const int row = c * 64 + lane;
    const float* ra = A + (size_t)row * 14;
    const float* rb = B + (size_t)row * 14;
    float4 a0 = *(const float4*)(ra + 0);
    float4 a1 = *(const float4*)(ra + 4);
    float4 a2 = *(const float4*)(ra + 8);
    float2 a3 = *(const float2*)(ra + 12);
    float4 b0 = *(const float4*)(rb + 0);
    float4 b1 = *(const float4*)(rb + 4);
    float4 b2 = *(const float4*)(rb + 8);
    float2 b3 = *(const float2*)(rb + 12);
    r.ea = IDA[row];
    r.eb = IDB[row];
    r.a[0]=a0.x; r.a[1]=a0.y; r.a[2]=a0.z; r.a[3]=a0.w;
    r.a[4]=a1.x; r.a[5]=a1.y; r.a[6]=a1.z; r.a[7]=a1.w;
    r.a[8]=a2.x; r.a[9]=a2.y; r.a[10]=a2.z; r.a[11]=a2.w;
    r.a[12]=a3.x; r.a[13]=a3.y;
    r.b[0]=b0.x; r.b[1]=b0.y; r.b[2]=b0.z; r.b[3]=b0.w;
    r.b[4]=b1.x; r.b[5]=b1.y; r.b[6]=b1.z; r.b[7]=b1.w;
    r.b[8]=b2.x; r.b[9]=b2.y; r.b[10]=b2.z; r.b[11]=b2.w;
    r.b[12]=b3.x; r.b[13]=b3.y;
    return r;
}

__device__ __forceinline__ void scatter_chunk(unsigned int* __restrict__ row32,
                                              const RowRegs& r) {
    const u4 z = {0u, 0u, 0u, 0u};
#pragma unroll
    for (int t = 0; t < 8; ++t) ((u4*)row32)[t] = z;   // zero dwords 0..31 (k=0..63)
    if (r.ea == r.eb) {
#pragma unroll
        for (int t = 0; t < 7; ++t)
            row32[7 * r.ea + t] = pkrtz(r.a[2*t] - r.b[2*t], r.a[2*t+1] - r.b[2*t+1]);
        // one-hots cancel: dwords 28..29 stay zero
    } else {
#pragma unroll
        for (int t = 0; t < 7; ++t)
            row32[7 * r.ea + t] = pkrtz(r.a[2*t], r.a[2*t+1]);
#pragma unroll
        for (int t = 0; t < 7; ++t)
            row32[7 * r.eb + t] = pkrtz(-r.b[2*t], -r.b[2*t+1]);
        const unsigned wa = 0x3C00u << ((r.ea & 1) * 16);   // +1.0h at k=56+ea
        const unsigned wb = 0xBC00u << ((r.eb & 1) * 16);   // -1.0h at k=56+eb
        const int ja = 28 + (r.ea >> 1), jb = 28 + (r.eb >> 1);
        if (ja == jb) row32[ja] = wa | wb;
        else { row32[ja] = wa; row32[jb] = wb; }
    }
}

__device__ __forceinline__ void compute_chunk(const unsigned int* __restrict__ sbuf,
                                              int sub, int quad, const h8* wf,
                                              float* ls) {
#pragma unroll
    for (int t = 0; t < 4; ++t) {
        const unsigned int* fr = sbuf + (t * 16 + sub) * LDSW + quad * 4;
        u4 lo = *(const u4*)fr;          // k = quad*8 .. +7
        u4 hi = *(const u4*)(fr + 16);   // k = 32+quad*8 .. +7
        const h8 e0 = __builtin_bit_cast(h8, lo);
        const h8 e1 = __builtin_bit_cast(h8, hi);
#pragma unroll
        for (int ct = 0; ct < 4; ++ct) {
            const f4 z = {0.0f, 0.0f, 0.0f, 0.0f};
            f4 acc = __builtin_amdgcn_mfma_f32_16x16x32_f16(e0, wf[ct * 2 + 0], z, 0, 0, 0);
            acc     = __builtin_amdgcn_mfma_f32_16x16x32_f16(e1, wf[ct * 2 + 1], acc, 0, 0, 0);
#pragma unroll
            for (int rr = 0; rr < 4; ++rr)
                ls[rr] = fmaf(acc[rr], acc[rr], ls[rr]);
        }
    }
}

__global__ void __launch_bounds__(64, 4)
frame_loss(const float* __restrict__ A, const float* __restrict__ B,
           const int* __restrict__ IDA, const int* __restrict__ IDB,
           const float* __restrict__ W, const float* __restrict__ BIAS,
           float* __restrict__ ws)
{
    __shared__ alignas(16) unsigned int s0[64 * LDSW];  // 9216 B (single buffer)

    const int lane = threadIdx.x;        // block = 1 wave
    const int sub  = lane & 15;
    const int quad = lane >> 4;

    // ---- W~ B-fragments in registers (once): frag f=ct*2+s, elem j:
    // k = s*32 + quad*8 + j, col c = ct*16 + sub. W~[k][c] = W (k<56), bias (56..59), 0.
    h8 wf[8];
#pragma unroll
    for (int ct = 0; ct < 4; ++ct)
#pragma unroll
        for (int s = 0; s < 2; ++s) {
            h8 f;
            const int c = ct * 16 + sub;
#pragma unroll
            for (int j = 0; j < 8; ++j) {
                const int k = s * 32 + quad * 8 + j;
                float v = 0.0f;
                if (k < 56)       v = W[k * 64 + c];           // (4,14,64) flat == W~ rows 0..55
                else if (k < 60)  v = BIAS[(k - 56) * 64 + c]; // bias rows 56..59
                f[j] = (_Float16)v;
            }
            wf[ct * 2 + s] = f;
        }

    float ls[4] = {0.0f, 0.0f, 0.0f, 0.0f};
    unsigned int* const myrow = s0 + lane * LDSW;
    const int stride = gridDim.x;

    int c = blockIdx.x;                         // grid <= 4096 < N_CHUNKS always
    RowRegs rr = load_chunk(c, lane, A, B, IDA, IDB);
    scatter_chunk(myrow, rr);

    while (true) {
        int n = c + stride;
        bool more = (n < N_CHUNKS);
        if (more) rr = load_chunk(n, lane, A, B, IDA, IDB);   // overlap with compute below
        compute_chunk(s0, sub, quad, wf, ls);
        if (!more) break;
        // Safe single-buffer: DS ops from this wave are serviced in issue
        // order, so these writes cannot bypass compute_chunk's reads.
        scatter_chunk(myrow, rr);
        c = n;
    }

    float lsum = ls[0] + ls[1] + ls[2] + ls[3];
#pragma unroll
    for (int off = 32; off > 0; off >>= 1)
        lsum += __shfl_down(lsum, off, 64);
    if (lane == 0)
        ws[blockIdx.x] = lsum;     // no atomic: per-block partial
}

__global__ void __launch_bounds__(256)
reduce_partials(const float* __restrict__ ws, float* __restrict__ out, int nblk)
{
    const int tid = threadIdx.x;
    float s = 0.0f;
    for (int i = tid; i < nblk; i += 256) s += ws[i];
#pragma unroll
    for (int off = 32; off > 0; off >>= 1)
        s += __shfl_down(s, off, 64);
    __shared__ float tmp[4];
    if ((tid & 63) == 0) tmp[tid >> 6] = s;
    __syncthreads();
    if (tid == 0)
        out[0] = (tmp[0] + tmp[1] + tmp[2] + tmp[3]) * (1.0f / 128000000.0f); // 1/(N*64)
}

extern "C" void kernel_launch(void* const* d_in, const int* in_sizes, int n_in,
                              void* d_out, int out_size, void* d_ws, size_t ws_size,
                              hipStream_t stream) {
    const float* A    = (const float*)d_in[0];
    const float* B    = (const float*)d_in[1];
    const int*   IDA  = (const int*)d_in[2];
    const int*   IDB  = (const int*)d_in[3];
    const float* W    = (const float*)d_in[4];
    const float* BIAS = (const float*)d_in[5];
    float* ws  = (float*)d_ws;     // needs NBLK*4 = 16 KB of scratch
    float* out = (float*)d_out;

    // fall back to the old 2048-block grid if the workspace is unexpectedly small
    const int nblk = (ws_size >= (size_t)NBLK * sizeof(float)) ? NBLK : 2048;

    frame_loss<<<dim3(nblk), dim3(64), 0, stream>>>(A, B, IDA, IDB, W, BIAS, ws);
    reduce_partials<<<dim3(1), dim3(256), 0, stream>>>(ws, out, nblk);
}